// Round 1
// baseline (401.324 us; speedup 1.0000x reference)
//
#include <hip/hip_runtime.h>
#include <cstdint>

// ---------------------------------------------------------------------------
// Causal self-attention block: qkv GEMM -> flash attention -> proj GEMM.
// All matmuls in bf16 MFMA (16x16x32), fp32 accumulate. fp32 in/out.
// B=4 S=2048 E=768 H=12 D=64.
// ---------------------------------------------------------------------------

typedef __bf16 bf16x8 __attribute__((ext_vector_type(8)));
typedef __bf16 bf16x4 __attribute__((ext_vector_type(4)));
typedef float  f32x4  __attribute__((ext_vector_type(4)));

#define MFMA16(a, b, c) __builtin_amdgcn_mfma_f32_16x16x32_bf16(a, b, c, 0, 0, 0)

static constexpr int Bb = 4, Ss = 2048, Ee = 768, Hh = 12, Dd = 64;

// async global->LDS, 16B per lane. LDS dest must be wave-uniform base;
// HW adds lane*16.
__device__ __forceinline__ void gl2lds16(const void* g, void* l) {
  __builtin_amdgcn_global_load_lds(
      (const __attribute__((address_space(1))) void*)g,
      (__attribute__((address_space(3))) void*)l, 16, 0, 0);
}

// ---------------------------------------------------------------------------
// prep kernels
// ---------------------------------------------------------------------------
__global__ void cast_f32_bf16(const float* __restrict__ x,
                              __bf16* __restrict__ y, int n) {
  int i = (blockIdx.x * blockDim.x + threadIdx.x) * 4;
  if (i < n) {
    float4 v = *(const float4*)(x + i);
    bf16x4 o = {(__bf16)v.x, (__bf16)v.y, (__bf16)v.z, (__bf16)v.w};
    *(bf16x4*)(y + i) = o;
  }
}

// W [K][N] f32 -> Wt [N][K] bf16 (64x64 LDS tile, conflict-free via +1 pad)
__global__ void transpose_cast(const float* __restrict__ W,
                               __bf16* __restrict__ Wt, int K, int N) {
  __shared__ float t[64][65];
  const int k0 = blockIdx.y * 64, n0 = blockIdx.x * 64;
#pragma unroll
  for (int i = 0; i < 16; ++i) {
    int lin = i * 256 + threadIdx.x;
    int r = lin >> 6, c = lin & 63;
    t[r][c] = W[(size_t)(k0 + r) * N + n0 + c];
  }
  __syncthreads();
#pragma unroll
  for (int i = 0; i < 16; ++i) {
    int lin = i * 256 + threadIdx.x;
    int r = lin >> 6, c = lin & 63;  // r: n offset, c: k offset
    Wt[(size_t)(n0 + r) * K + k0 + c] = (__bf16)t[c][r];
  }
}

// ---------------------------------------------------------------------------
// m97-style GEMM: C[M,N] = A[M,K] @ Bt[N,K]^T, 128x128 tile, BK=32,
// 4 waves each computing 64x64 (4x4 16x16 frags).
// MODE 0: qkv epilogue (bias, split to Q/K [B,H,S,D] and V^T [B,H,D,S], bf16)
// MODE 1: proj epilogue (bias, fp32 out)
// ---------------------------------------------------------------------------
template <int MODE>
__global__ __launch_bounds__(256) void gemm_bt(
    const __bf16* __restrict__ A, const __bf16* __restrict__ Bt,
    const float* __restrict__ bias, __bf16* __restrict__ Qb,
    __bf16* __restrict__ Kb, __bf16* __restrict__ VTb,
    float* __restrict__ out, int K, int N) {
  __shared__ __align__(16) __bf16 As[128 * 32];
  __shared__ __align__(16) __bf16 Bs[128 * 32];
  const int tid = threadIdx.x;
  const int wave = tid >> 6, lane = tid & 63;
  const int quad = lane >> 4, c16 = lane & 15;
  const int m0 = blockIdx.y * 128, n0 = blockIdx.x * 128;
  const int wm = (wave >> 1) * 64, wn = (wave & 1) * 64;

  f32x4 acc[4][4] = {};

  for (int k0 = 0; k0 < K; k0 += 32) {
    __syncthreads();
#pragma unroll
    for (int i = 0; i < 2; ++i) {
      const int cb = (i * 4 + wave) * 64;  // wave-uniform chunk base
      const int c = cb + lane;             // chunk = 8 bf16 of one row
      const int row = c >> 2, kk = (c & 3) * 8;
      gl2lds16(&A[(size_t)(m0 + row) * K + k0 + kk], &As[cb * 8]);
      gl2lds16(&Bt[(size_t)(n0 + row) * K + k0 + kk], &Bs[cb * 8]);
    }
    __syncthreads();
    bf16x8 af[4], bf[4];
#pragma unroll
    for (int mi = 0; mi < 4; ++mi)
      af[mi] = *(const bf16x8*)&As[(wm + mi * 16 + c16) * 32 + quad * 8];
#pragma unroll
    for (int ni = 0; ni < 4; ++ni)
      bf[ni] = *(const bf16x8*)&Bs[(wn + ni * 16 + c16) * 32 + quad * 8];
#pragma unroll
    for (int mi = 0; mi < 4; ++mi)
#pragma unroll
      for (int ni = 0; ni < 4; ++ni)
        acc[mi][ni] = MFMA16(af[mi], bf[ni], acc[mi][ni]);
  }

  // epilogue: C/D layout col=lane&15, row=quad*4+reg
#pragma unroll
  for (int mi = 0; mi < 4; ++mi) {
#pragma unroll
    for (int ni = 0; ni < 4; ++ni) {
      const int gcol = n0 + wn + ni * 16 + c16;
      const float bv = bias[gcol];
      const int growb = m0 + wm + mi * 16 + quad * 4;
      if (MODE == 0) {
        const int which = gcol / Ee;
        const int e = gcol - which * Ee;
        const int hh = e >> 6, dd = e & 63;
#pragma unroll
        for (int r = 0; r < 4; ++r) {
          const int row = growb + r;
          const int bb = row >> 11, ss = row & 2047;  // S=2048
          const float v = acc[mi][ni][r] + bv;
          const size_t bh = (size_t)(bb * Hh + hh);
          if (which == 0)
            Qb[(bh * Ss + ss) * Dd + dd] = (__bf16)v;
          else if (which == 1)
            Kb[(bh * Ss + ss) * Dd + dd] = (__bf16)v;
          else
            VTb[(bh * Dd + dd) * Ss + ss] = (__bf16)v;
        }
      } else {
#pragma unroll
        for (int r = 0; r < 4; ++r) {
          const int row = growb + r;
          out[(size_t)row * N + gcol] = acc[mi][ni][r] + bv;
        }
      }
    }
  }
}

// ---------------------------------------------------------------------------
// flash attention: block = (b, h, 128-query tile), 4 waves x 32 queries.
// K-tile = 64 keys. Q,K in [B,H,S,D] bf16; V pre-transposed [B,H,D,S] bf16.
// Online softmax; P goes through wave-private LDS to convert C->A layout.
// ---------------------------------------------------------------------------
__global__ __launch_bounds__(256) void flash_attn(
    const __bf16* __restrict__ Qb, const __bf16* __restrict__ Kb,
    const __bf16* __restrict__ VTb, const int* __restrict__ amask,
    __bf16* __restrict__ Yb) {
  const int qt = (int)(gridDim.x - 1 - blockIdx.x);  // heavy tiles first
  const int h = blockIdx.y, b = blockIdx.z;
  const int tid = threadIdx.x, w = tid >> 6, lane = tid & 63;
  const int quad = lane >> 4, c16 = lane & 15;
  const int q0 = qt * 128;
  const int wq = q0 + w * 32;
  const size_t bh = (size_t)(b * Hh + h);
  const __bf16* Qp = Qb + bh * Ss * Dd;
  const __bf16* Kp = Kb + bh * Ss * Dd;
  const __bf16* Vp = VTb + bh * Dd * Ss;

  __shared__ __align__(16) __bf16 Kt[64][72];      // [key][d], padded
  __shared__ __align__(16) __bf16 Vt[64][72];      // [d][key], padded
  __shared__ __align__(16) __bf16 Pt[4][32][72];   // per-wave P, padded
  __shared__ int am[64];

  // Q fragments (A layout: m=lane&15, k=quad*8+j), resident in registers
  bf16x8 qa[2][2];
#pragma unroll
  for (int si = 0; si < 2; ++si)
#pragma unroll
    for (int ks = 0; ks < 2; ++ks)
      qa[si][ks] = *(const bf16x8*)&Qp[(size_t)(wq + si * 16 + c16) * Dd +
                                       ks * 32 + quad * 8];

  f32x4 yacc[2][4] = {};
  float mrow[2][4], lrow[2][4];
#pragma unroll
  for (int si = 0; si < 2; ++si)
#pragma unroll
    for (int r = 0; r < 4; ++r) {
      mrow[si][r] = -1e30f;
      lrow[si][r] = 0.f;
    }

  const int nkt = qt * 2 + 2;  // causal bound for this q-tile
  for (int kt = 0; kt < nkt; ++kt) {
    const int k0 = kt * 64;
    __syncthreads();  // protect LDS tiles from previous iteration's readers
#pragma unroll
    for (int i = 0; i < 2; ++i) {
      const int c = i * 256 + tid;  // 512 chunks of 8 bf16
      const int r8 = c >> 3, o8 = (c & 7) * 8;
      *(bf16x8*)&Kt[r8][o8] = *(const bf16x8*)&Kp[(size_t)(k0 + r8) * Dd + o8];
      *(bf16x8*)&Vt[r8][o8] = *(const bf16x8*)&Vp[(size_t)r8 * Ss + k0 + o8];
    }
    if (tid < 64) am[tid] = amask[b * Ss + k0 + tid];
    __syncthreads();

    // S = Q K^T * scale, masked. C layout: col(key)=c16, row(q)=quad*4+r
    float p[2][4][4];
#pragma unroll
    for (int si = 0; si < 2; ++si) {
#pragma unroll
      for (int kk = 0; kk < 4; ++kk) {
        f32x4 s = {};
        bf16x8 kb0 = *(const bf16x8*)&Kt[kk * 16 + c16][quad * 8];
        bf16x8 kb1 = *(const bf16x8*)&Kt[kk * 16 + c16][32 + quad * 8];
        s = MFMA16(qa[si][0], kb0, s);
        s = MFMA16(qa[si][1], kb1, s);
        const int key = k0 + kk * 16 + c16;
        const bool kv = (am[kk * 16 + c16] != 0);
#pragma unroll
        for (int r = 0; r < 4; ++r) {
          const int q = wq + si * 16 + quad * 4 + r;
          p[si][kk][r] = (kv && key <= q) ? s[r] * 0.125f : -1e30f;
        }
      }
    }

    // online softmax: row spans 16 lanes (one quad) x 4 kk frags
#pragma unroll
    for (int si = 0; si < 2; ++si) {
#pragma unroll
      for (int r = 0; r < 4; ++r) {
        float mx = fmaxf(fmaxf(p[si][0][r], p[si][1][r]),
                         fmaxf(p[si][2][r], p[si][3][r]));
#pragma unroll
        for (int off = 1; off < 16; off <<= 1)
          mx = fmaxf(mx, __shfl_xor(mx, off));
        const float mnew = fmaxf(mrow[si][r], mx);
        const float alpha = __expf(mrow[si][r] - mnew);
        float rs = 0.f;
#pragma unroll
        for (int kk = 0; kk < 4; ++kk) {
          const float e = __expf(p[si][kk][r] - mnew);
          p[si][kk][r] = e;
          rs += e;
        }
#pragma unroll
        for (int off = 1; off < 16; off <<= 1) rs += __shfl_xor(rs, off);
        lrow[si][r] = lrow[si][r] * alpha + rs;
        mrow[si][r] = mnew;
#pragma unroll
        for (int g = 0; g < 4; ++g) yacc[si][g][r] *= alpha;
      }
    }

    // P: C layout -> LDS -> A layout (wave-private region, no barrier)
#pragma unroll
    for (int si = 0; si < 2; ++si)
#pragma unroll
      for (int kk = 0; kk < 4; ++kk)
#pragma unroll
        for (int r = 0; r < 4; ++r)
          Pt[w][si * 16 + quad * 4 + r][kk * 16 + c16] = (__bf16)p[si][kk][r];

#pragma unroll
    for (int si = 0; si < 2; ++si) {
      bf16x8 pa0 = *(const bf16x8*)&Pt[w][si * 16 + c16][quad * 8];
      bf16x8 pa1 = *(const bf16x8*)&Pt[w][si * 16 + c16][32 + quad * 8];
#pragma unroll
      for (int g = 0; g < 4; ++g) {
        bf16x8 vb0 = *(const bf16x8*)&Vt[g * 16 + c16][quad * 8];
        bf16x8 vb1 = *(const bf16x8*)&Vt[g * 16 + c16][32 + quad * 8];
        yacc[si][g] = MFMA16(pa0, vb0, yacc[si][g]);
        yacc[si][g] = MFMA16(pa1, vb1, yacc[si][g]);
      }
    }
  }

  // normalize and write Y [B,S,E] bf16 (GEMM2's A operand)
#pragma unroll
  for (int si = 0; si < 2; ++si)
#pragma unroll
    for (int r = 0; r < 4; ++r) {
      const float inv = 1.f / lrow[si][r];
      const int q = wq + si * 16 + quad * 4 + r;
#pragma unroll
      for (int g = 0; g < 4; ++g)
        Yb[(size_t)(b * Ss + q) * Ee + h * Dd + g * 16 + c16] =
            (__bf16)(yacc[si][g][r] * inv);
    }
}

// ---------------------------------------------------------------------------
// launch
// ---------------------------------------------------------------------------
extern "C" void kernel_launch(void* const* d_in, const int* in_sizes, int n_in,
                              void* d_out, int out_size, void* d_ws,
                              size_t ws_size, hipStream_t stream) {
  const float* x      = (const float*)d_in[0];
  const float* W_attn = (const float*)d_in[1];
  const float* b_attn = (const float*)d_in[2];
  const float* W_proj = (const float*)d_in[3];
  const float* b_proj = (const float*)d_in[4];
  const int* att_mask = (const int*)d_in[5];
  float* out = (float*)d_out;

  // workspace layout (bytes), total ~55 MB; Yb aliases xb (x dead after gemm1)
  char* ws = (char*)d_ws;
  __bf16* xb  = (__bf16*)(ws);              // 12,582,912  x as bf16 / later Y
  __bf16* Wat = (__bf16*)(ws + 12582912);   //  3,538,944  W_attn^T bf16
  __bf16* Wpt = (__bf16*)(ws + 16121856);   //  1,179,648  W_proj^T bf16
  __bf16* Qb  = (__bf16*)(ws + 17301504);   // 12,582,912  Q [B,H,S,D]
  __bf16* Kb  = (__bf16*)(ws + 29884416);   // 12,582,912  K [B,H,S,D]
  __bf16* VTb = (__bf16*)(ws + 42467328);   // 12,582,912  V^T [B,H,D,S]
  __bf16* Yb  = xb;

  cast_f32_bf16<<<6144, 256, 0, stream>>>(x, xb, Bb * Ss * Ee);
  transpose_cast<<<dim3(36, 12), 256, 0, stream>>>(W_attn, Wat, Ee, 3 * Ee);
  transpose_cast<<<dim3(12, 12), 256, 0, stream>>>(W_proj, Wpt, Ee, Ee);

  // qkv: [8192,768] @ [768,2304]
  gemm_bt<0><<<dim3(18, 64), 256, 0, stream>>>(xb, Wat, b_attn, Qb, Kb, VTb,
                                               nullptr, Ee, 3 * Ee);
  // attention: 16 q-tiles x 12 heads x 4 batches
  flash_attn<<<dim3(16, Hh, Bb), 256, 0, stream>>>(Qb, Kb, VTb, att_mask, Yb);
  // proj: [8192,768] @ [768,768]
  gemm_bt<1><<<dim3(6, 64), 256, 0, stream>>>(Yb, Wpt, b_proj, nullptr,
                                              nullptr, nullptr, out, Ee, Ee);
}

// Round 2
// 277.195 us; speedup vs baseline: 1.4478x; 1.4478x over previous
//
#include <hip/hip_runtime.h>
#include <cstdint>

// ---------------------------------------------------------------------------
// Causal self-attention block: qkv GEMM -> flash attention -> proj GEMM.
// All matmuls in bf16 MFMA (16x16x32), fp32 accumulate. fp32 in/out.
// B=4 S=2048 E=768 H=12 D=64.
// ---------------------------------------------------------------------------

typedef __bf16 bf16x8 __attribute__((ext_vector_type(8)));
typedef __bf16 bf16x4 __attribute__((ext_vector_type(4)));
typedef float  f32x4  __attribute__((ext_vector_type(4)));

#define MFMA16(a, b, c) __builtin_amdgcn_mfma_f32_16x16x32_bf16(a, b, c, 0, 0, 0)

static constexpr int Bb = 4, Ss = 2048, Ee = 768, Hh = 12, Dd = 64;

// async global->LDS, 16B per lane. LDS dest must be wave-uniform base;
// HW adds lane*16.
__device__ __forceinline__ void gl2lds16(const void* g, void* l) {
  __builtin_amdgcn_global_load_lds(
      (const __attribute__((address_space(1))) void*)g,
      (__attribute__((address_space(3))) void*)l, 16, 0, 0);
}

// ---------------------------------------------------------------------------
// prep kernels
// ---------------------------------------------------------------------------
__global__ void cast_f32_bf16(const float* __restrict__ x,
                              __bf16* __restrict__ y, int n) {
  int i = (blockIdx.x * blockDim.x + threadIdx.x) * 4;
  if (i < n) {
    float4 v = *(const float4*)(x + i);
    bf16x4 o = {(__bf16)v.x, (__bf16)v.y, (__bf16)v.z, (__bf16)v.w};
    *(bf16x4*)(y + i) = o;
  }
}

// W [K][N] f32 -> Wt [N][K] bf16 (64x64 LDS tile, conflict-free via +1 pad)
__global__ void transpose_cast(const float* __restrict__ W,
                               __bf16* __restrict__ Wt, int K, int N) {
  __shared__ float t[64][65];
  const int k0 = blockIdx.y * 64, n0 = blockIdx.x * 64;
#pragma unroll
  for (int i = 0; i < 16; ++i) {
    int lin = i * 256 + threadIdx.x;
    int r = lin >> 6, c = lin & 63;
    t[r][c] = W[(size_t)(k0 + r) * N + n0 + c];
  }
  __syncthreads();
#pragma unroll
  for (int i = 0; i < 16; ++i) {
    int lin = i * 256 + threadIdx.x;
    int r = lin >> 6, c = lin & 63;  // r: n offset, c: k offset
    Wt[(size_t)(n0 + r) * K + k0 + c] = (__bf16)t[c][r];
  }
}

// ---------------------------------------------------------------------------
// m97-style GEMM: C[M,N] = A[M,K] @ Bt[N,K]^T, 128x128 tile, BK=32,
// 4 waves each computing 64x64 (4x4 16x16 frags).
// MODE 0: qkv epilogue (bias, split to Q/K [B,H,S,D] and V^T [B,H,D,S], bf16)
// MODE 1: proj epilogue (bias, fp32 out)
// ---------------------------------------------------------------------------
template <int MODE>
__global__ __launch_bounds__(256) void gemm_bt(
    const __bf16* __restrict__ A, const __bf16* __restrict__ Bt,
    const float* __restrict__ bias, __bf16* __restrict__ Qb,
    __bf16* __restrict__ Kb, __bf16* __restrict__ VTb,
    float* __restrict__ out, int K, int N) {
  __shared__ __align__(16) __bf16 As[128 * 32];
  __shared__ __align__(16) __bf16 Bs[128 * 32];
  const int tid = threadIdx.x;
  const int wave = tid >> 6, lane = tid & 63;
  const int quad = lane >> 4, c16 = lane & 15;
  const int m0 = blockIdx.y * 128, n0 = blockIdx.x * 128;
  const int wm = (wave >> 1) * 64, wn = (wave & 1) * 64;

  f32x4 acc[4][4] = {};

  for (int k0 = 0; k0 < K; k0 += 32) {
    __syncthreads();
#pragma unroll
    for (int i = 0; i < 2; ++i) {
      const int cb = (i * 4 + wave) * 64;  // wave-uniform chunk base
      const int c = cb + lane;             // chunk = 8 bf16 of one row
      const int row = c >> 2, kk = (c & 3) * 8;
      gl2lds16(&A[(size_t)(m0 + row) * K + k0 + kk], &As[cb * 8]);
      gl2lds16(&Bt[(size_t)(n0 + row) * K + k0 + kk], &Bs[cb * 8]);
    }
    __syncthreads();
    bf16x8 af[4], bf[4];
#pragma unroll
    for (int mi = 0; mi < 4; ++mi)
      af[mi] = *(const bf16x8*)&As[(wm + mi * 16 + c16) * 32 + quad * 8];
#pragma unroll
    for (int ni = 0; ni < 4; ++ni)
      bf[ni] = *(const bf16x8*)&Bs[(wn + ni * 16 + c16) * 32 + quad * 8];
#pragma unroll
    for (int mi = 0; mi < 4; ++mi)
#pragma unroll
      for (int ni = 0; ni < 4; ++ni)
        acc[mi][ni] = MFMA16(af[mi], bf[ni], acc[mi][ni]);
  }

  // epilogue: C/D layout col=lane&15, row=quad*4+reg
#pragma unroll
  for (int mi = 0; mi < 4; ++mi) {
#pragma unroll
    for (int ni = 0; ni < 4; ++ni) {
      const int gcol = n0 + wn + ni * 16 + c16;
      const float bv = bias[gcol];
      const int growb = m0 + wm + mi * 16 + quad * 4;
      if (MODE == 0) {
        const int which = gcol / Ee;
        const int e = gcol - which * Ee;
        const int hh = e >> 6, dd = e & 63;
#pragma unroll
        for (int r = 0; r < 4; ++r) {
          const int row = growb + r;
          const int bb = row >> 11, ss = row & 2047;  // S=2048
          const float v = acc[mi][ni][r] + bv;
          const size_t bh = (size_t)(bb * Hh + hh);
          if (which == 0)
            Qb[(bh * Ss + ss) * Dd + dd] = (__bf16)v;
          else if (which == 1)
            Kb[(bh * Ss + ss) * Dd + dd] = (__bf16)v;
          else
            VTb[(bh * Dd + dd) * Ss + ss] = (__bf16)v;
        }
      } else {
#pragma unroll
        for (int r = 0; r < 4; ++r) {
          const int row = growb + r;
          out[(size_t)row * N + gcol] = acc[mi][ni][r] + bv;
        }
      }
    }
  }
}

// ---------------------------------------------------------------------------
// flash attention v2: block = (b, h, PAIR of 64-query tiles {31-pr, pr}).
// Every block does exactly 33 key-tile iterations -> perfect balance.
// Each wave owns 16 queries (q = lane&15). We compute S^T = K @ Q^T so the
// softmax row is per-lane (2 shuffles instead of 8 per row), and Y^T = V^T@P^T
// with a shared k-permutation so S^T's C-layout registers ARE the B-operand
// fragment -- no LDS roundtrip, no lane shuffles for P.
// ---------------------------------------------------------------------------
__global__ __launch_bounds__(256) void flash_attn(
    const __bf16* __restrict__ Qb, const __bf16* __restrict__ Kb,
    const __bf16* __restrict__ VTb, const int* __restrict__ amask,
    __bf16* __restrict__ Yb) {
  const int pr = blockIdx.x;  // 0..15 -> tiles {31-pr, pr}
  const int h = blockIdx.y, b = blockIdx.z;
  const int tid = threadIdx.x, w = tid >> 6, lane = tid & 63;
  const int quad = lane >> 4, c16 = lane & 15;
  const size_t bh = (size_t)(b * Hh + h);
  const __bf16* Qp = Qb + bh * Ss * Dd;
  const __bf16* Kp = Kb + bh * Ss * Dd;
  const __bf16* Vp = VTb + bh * Dd * Ss;

  __shared__ __align__(16) __bf16 Kt[64][72];  // [key][d], padded
  __shared__ __align__(16) __bf16 Vt[64][72];  // [d][key], padded
  __shared__ int am[64];

#pragma unroll
  for (int ti = 0; ti < 2; ++ti) {
    const int qt = ti ? pr : (31 - pr);
    const int qg = qt * 64 + w * 16 + c16;  // this lane's query row
    // Q fragment, also valid as MFMA B-operand (A/B lane layouts coincide)
    const bf16x8 qa0 = *(const bf16x8*)&Qp[(size_t)qg * Dd + quad * 8];
    const bf16x8 qa1 = *(const bf16x8*)&Qp[(size_t)qg * Dd + 32 + quad * 8];

    f32x4 yacc[4] = {};           // Y^T[d = dt*16+quad*4+r][q = c16]
    float m_i = -1e30f, l_i = 0.f;

    for (int kt = 0; kt <= qt; ++kt) {
      const int k0 = kt * 64;
      __syncthreads();  // previous iteration's readers done
#pragma unroll
      for (int i = 0; i < 2; ++i) {
        const int c = i * 256 + tid;  // 512 chunks of 8 bf16 each
        const int r8 = c >> 3, o8 = (c & 7) * 8;
        *(bf16x8*)&Kt[r8][o8] = *(const bf16x8*)&Kp[(size_t)(k0 + r8) * Dd + o8];
        *(bf16x8*)&Vt[r8][o8] = *(const bf16x8*)&Vp[(size_t)r8 * Ss + k0 + o8];
      }
      if (tid < 64) am[tid] = amask[b * Ss + k0 + tid];
      __syncthreads();

      // S^T = K @ Q^T: C layout -> lane holds key = kk*16+quad*4+r, q = c16
      float p[4][4];
#pragma unroll
      for (int kk = 0; kk < 4; ++kk) {
        f32x4 s = {};
        const bf16x8 kf0 = *(const bf16x8*)&Kt[kk * 16 + c16][quad * 8];
        const bf16x8 kf1 = *(const bf16x8*)&Kt[kk * 16 + c16][32 + quad * 8];
        s = MFMA16(kf0, qa0, s);
        s = MFMA16(kf1, qa1, s);
        const bool diag = (kt == qt);
#pragma unroll
        for (int r = 0; r < 4; ++r) {
          const int kl = kk * 16 + quad * 4 + r;
          const bool ok = (am[kl] != 0) && (!diag || (k0 + kl <= qg));
          p[kk][r] = ok ? s[r] * 0.125f : -1e30f;
        }
      }

      // online softmax, row = this lane's q; reduce over quads (xor 16,32)
      float mx = p[0][0];
#pragma unroll
      for (int kk = 0; kk < 4; ++kk)
#pragma unroll
        for (int r = 0; r < 4; ++r) mx = fmaxf(mx, p[kk][r]);
      mx = fmaxf(mx, __shfl_xor(mx, 16));
      mx = fmaxf(mx, __shfl_xor(mx, 32));
      const float mnew = fmaxf(m_i, mx);
      const float alpha = __expf(m_i - mnew);
      float rs = 0.f;
#pragma unroll
      for (int kk = 0; kk < 4; ++kk)
#pragma unroll
        for (int r = 0; r < 4; ++r) {
          const float e = __expf(p[kk][r] - mnew);
          p[kk][r] = e;
          rs += e;
        }
      rs += __shfl_xor(rs, 16);
      rs += __shfl_xor(rs, 32);
      if (mnew < -1e29f) rs = 0.f;  // fully-masked tile: don't pollute l
      l_i = l_i * alpha + rs;
      m_i = mnew;
#pragma unroll
      for (int dt = 0; dt < 4; ++dt) yacc[dt] *= alpha;

      // P^T as B-operand under shared k-permutation:
      //   k = quad*8+j  <->  key = 32t + 16*(j>>2) + quad*4 + (j&3)
      // so B-frag reg j = p[2t + (j>>2)][j&3] -- straight from registers.
      bf16x8 pf[2];
#pragma unroll
      for (int t = 0; t < 2; ++t) {
        bf16x8 f;
#pragma unroll
        for (int j = 0; j < 4; ++j) {
          f[j] = (__bf16)p[2 * t][j];
          f[4 + j] = (__bf16)p[2 * t + 1][j];
        }
        pf[t] = f;
      }

      // Y^T += V^T @ P^T. A-frag uses the same key permutation:
      // reg j<4: Vt[d][32t + quad*4 + j], reg j>=4: Vt[d][32t+16 + quad*4 + (j&3)]
#pragma unroll
      for (int dt = 0; dt < 4; ++dt) {
        const __bf16* vrow = &Vt[dt * 16 + c16][0];
#pragma unroll
        for (int t = 0; t < 2; ++t) {
          const bf16x4 v0 = *(const bf16x4*)&vrow[t * 32 + quad * 4];
          const bf16x4 v1 = *(const bf16x4*)&vrow[t * 32 + 16 + quad * 4];
          bf16x8 vf;
#pragma unroll
          for (int j = 0; j < 4; ++j) {
            vf[j] = v0[j];
            vf[4 + j] = v1[j];
          }
          yacc[dt] = MFMA16(vf, pf[t], yacc[dt]);
        }
      }
    }

    // normalize, write Y [B,S,E] bf16 (4x 8B stores per lane)
    const float inv = 1.f / l_i;
#pragma unroll
    for (int dt = 0; dt < 4; ++dt) {
      bf16x4 o;
#pragma unroll
      for (int r = 0; r < 4; ++r) o[r] = (__bf16)(yacc[dt][r] * inv);
      *(bf16x4*)&Yb[(size_t)(b * Ss + qg) * Ee + h * Dd + dt * 16 + quad * 4] = o;
    }
  }
}

// ---------------------------------------------------------------------------
// launch
// ---------------------------------------------------------------------------
extern "C" void kernel_launch(void* const* d_in, const int* in_sizes, int n_in,
                              void* d_out, int out_size, void* d_ws,
                              size_t ws_size, hipStream_t stream) {
  const float* x      = (const float*)d_in[0];
  const float* W_attn = (const float*)d_in[1];
  const float* b_attn = (const float*)d_in[2];
  const float* W_proj = (const float*)d_in[3];
  const float* b_proj = (const float*)d_in[4];
  const int* att_mask = (const int*)d_in[5];
  float* out = (float*)d_out;

  // workspace layout (bytes), total ~55 MB; Yb aliases xb (x dead after gemm1)
  char* ws = (char*)d_ws;
  __bf16* xb  = (__bf16*)(ws);              // 12,582,912  x as bf16 / later Y
  __bf16* Wat = (__bf16*)(ws + 12582912);   //  3,538,944  W_attn^T bf16
  __bf16* Wpt = (__bf16*)(ws + 16121856);   //  1,179,648  W_proj^T bf16
  __bf16* Qb  = (__bf16*)(ws + 17301504);   // 12,582,912  Q [B,H,S,D]
  __bf16* Kb  = (__bf16*)(ws + 29884416);   // 12,582,912  K [B,H,S,D]
  __bf16* VTb = (__bf16*)(ws + 42467328);   // 12,582,912  V^T [B,H,D,S]
  __bf16* Yb  = xb;

  cast_f32_bf16<<<6144, 256, 0, stream>>>(x, xb, Bb * Ss * Ee);
  transpose_cast<<<dim3(36, 12), 256, 0, stream>>>(W_attn, Wat, Ee, 3 * Ee);
  transpose_cast<<<dim3(12, 12), 256, 0, stream>>>(W_proj, Wpt, Ee, Ee);

  // qkv: [8192,768] @ [768,2304]
  gemm_bt<0><<<dim3(18, 64), 256, 0, stream>>>(xb, Wat, b_attn, Qb, Kb, VTb,
                                               nullptr, Ee, 3 * Ee);
  // attention: 16 balanced tile-pairs x 12 heads x 4 batches
  flash_attn<<<dim3(16, Hh, Bb), 256, 0, stream>>>(Qb, Kb, VTb, att_mask, Yb);
  // proj: [8192,768] @ [768,768]
  gemm_bt<1><<<dim3(6, 64), 256, 0, stream>>>(Yb, Wpt, b_proj, nullptr,
                                              nullptr, nullptr, out, Ee, Ee);
}

// Round 3
// 237.843 us; speedup vs baseline: 1.6873x; 1.1655x over previous
//
#include <hip/hip_runtime.h>
#include <cstdint>

// ---------------------------------------------------------------------------
// Causal self-attention block: qkv GEMM -> flash attention (32x32 MFMA) ->
// proj GEMM. bf16 MFMA, fp32 accumulate. fp32 in/out.
// B=4 S=2048 E=768 H=12 D=64.
// ---------------------------------------------------------------------------

typedef __bf16 bf16x8 __attribute__((ext_vector_type(8)));
typedef __bf16 bf16x4 __attribute__((ext_vector_type(4)));
typedef float  f32x4  __attribute__((ext_vector_type(4)));
typedef float  f32x16 __attribute__((ext_vector_type(16)));

#define MFMA16(a, b, c) __builtin_amdgcn_mfma_f32_16x16x32_bf16(a, b, c, 0, 0, 0)
#define MFMA32(a, b, c) __builtin_amdgcn_mfma_f32_32x32x16_bf16(a, b, c, 0, 0, 0)

static constexpr int Bb = 4, Ss = 2048, Ee = 768, Hh = 12, Dd = 64;

__device__ __forceinline__ void gl2lds16(const void* g, void* l) {
  __builtin_amdgcn_global_load_lds(
      (const __attribute__((address_space(1))) void*)g,
      (__attribute__((address_space(3))) void*)l, 16, 0, 0);
}

// ---------------------------------------------------------------------------
// prep kernels
// ---------------------------------------------------------------------------
__global__ void cast_f32_bf16(const float* __restrict__ x,
                              __bf16* __restrict__ y, int n) {
  int i = (blockIdx.x * blockDim.x + threadIdx.x) * 4;
  if (i < n) {
    float4 v = *(const float4*)(x + i);
    bf16x4 o = {(__bf16)v.x, (__bf16)v.y, (__bf16)v.z, (__bf16)v.w};
    *(bf16x4*)(y + i) = o;
  }
}

__global__ void transpose_cast(const float* __restrict__ W,
                               __bf16* __restrict__ Wt, int K, int N) {
  __shared__ float t[64][65];
  const int k0 = blockIdx.y * 64, n0 = blockIdx.x * 64;
#pragma unroll
  for (int i = 0; i < 16; ++i) {
    int lin = i * 256 + threadIdx.x;
    int r = lin >> 6, c = lin & 63;
    t[r][c] = W[(size_t)(k0 + r) * N + n0 + c];
  }
  __syncthreads();
#pragma unroll
  for (int i = 0; i < 16; ++i) {
    int lin = i * 256 + threadIdx.x;
    int r = lin >> 6, c = lin & 63;
    Wt[(size_t)(n0 + r) * K + k0 + c] = (__bf16)t[c][r];
  }
}

// ---------------------------------------------------------------------------
// m97-style GEMM: C[M,N] = A[M,K] @ Bt[N,K]^T, 128x128 tile, BK=32.
// MODE 0: qkv epilogue (bias; Q prescaled by 1/8; V^T packed stores)
// MODE 1: proj epilogue (bias, fp32 out)
// ---------------------------------------------------------------------------
template <int MODE>
__global__ __launch_bounds__(256) void gemm_bt(
    const __bf16* __restrict__ A, const __bf16* __restrict__ Bt,
    const float* __restrict__ bias, __bf16* __restrict__ Qb,
    __bf16* __restrict__ Kb, __bf16* __restrict__ VTb,
    float* __restrict__ out, int K, int N) {
  __shared__ __align__(16) __bf16 As[128 * 32];
  __shared__ __align__(16) __bf16 Bs[128 * 32];
  const int tid = threadIdx.x;
  const int wave = tid >> 6, lane = tid & 63;
  const int quad = lane >> 4, c16 = lane & 15;
  const int m0 = blockIdx.y * 128, n0 = blockIdx.x * 128;
  const int wm = (wave >> 1) * 64, wn = (wave & 1) * 64;

  f32x4 acc[4][4] = {};

  for (int k0 = 0; k0 < K; k0 += 32) {
    __syncthreads();
#pragma unroll
    for (int i = 0; i < 2; ++i) {
      const int cb = (i * 4 + wave) * 64;
      const int c = cb + lane;
      const int row = c >> 2, kk = (c & 3) * 8;
      gl2lds16(&A[(size_t)(m0 + row) * K + k0 + kk], &As[cb * 8]);
      gl2lds16(&Bt[(size_t)(n0 + row) * K + k0 + kk], &Bs[cb * 8]);
    }
    __syncthreads();
    bf16x8 af[4], bf[4];
#pragma unroll
    for (int mi = 0; mi < 4; ++mi)
      af[mi] = *(const bf16x8*)&As[(wm + mi * 16 + c16) * 32 + quad * 8];
#pragma unroll
    for (int ni = 0; ni < 4; ++ni)
      bf[ni] = *(const bf16x8*)&Bs[(wn + ni * 16 + c16) * 32 + quad * 8];
#pragma unroll
    for (int mi = 0; mi < 4; ++mi)
#pragma unroll
      for (int ni = 0; ni < 4; ++ni)
        acc[mi][ni] = MFMA16(af[mi], bf[ni], acc[mi][ni]);
  }

#pragma unroll
  for (int mi = 0; mi < 4; ++mi) {
#pragma unroll
    for (int ni = 0; ni < 4; ++ni) {
      const int gcol = n0 + wn + ni * 16 + c16;
      const float bv = bias[gcol];
      const int growb = m0 + wm + mi * 16 + quad * 4;
      if (MODE == 0) {
        const int which = gcol / Ee;
        const int e = gcol - which * Ee;
        const int hh = e >> 6, dd = e & 63;
        const int bb = growb >> 11, ss = growb & 2047;  // 4 rows share bb
        const size_t bh = (size_t)(bb * Hh + hh);
        if (which == 2) {  // V^T: 4 consecutive ss -> one packed store
          bf16x4 o;
#pragma unroll
          for (int r = 0; r < 4; ++r) o[r] = (__bf16)(acc[mi][ni][r] + bv);
          *(bf16x4*)&VTb[(bh * Dd + dd) * Ss + ss] = o;
        } else if (which == 0) {  // Q, prescaled by softmax scale 1/8
#pragma unroll
          for (int r = 0; r < 4; ++r)
            Qb[(bh * Ss + ss + r) * Dd + dd] =
                (__bf16)((acc[mi][ni][r] + bv) * 0.125f);
        } else {  // K
#pragma unroll
          for (int r = 0; r < 4; ++r)
            Kb[(bh * Ss + ss + r) * Dd + dd] = (__bf16)(acc[mi][ni][r] + bv);
        }
      } else {
#pragma unroll
        for (int r = 0; r < 4; ++r)
          out[(size_t)(growb + r) * N + gcol] = acc[mi][ni][r] + bv;
      }
    }
  }
}

// ---------------------------------------------------------------------------
// flash attention v3: 32x32x16 MFMA. Block = (b,h,128-q tile), 4 waves x 32q.
// S^T = K @ Q^T (C rows = keys, cols = q -> softmax row per-lane, 1 shuffle).
// Y^T = V^T @ P^T where P^T's B-fragment = S^T's C-registers directly, via a
// shared k-slot permutation baked into the LDS layouts:
//   slot sigma (0..15) <-> offset 8*((sigma&7)>>2)... concretely
//   XtP[row][16w + 8h + 4u + r] = X[row][16w + 8u + 4h + r].
// Grid: flat 768, XCD-swizzled so all 16 tiles of one (b,h) share an XCD L2;
// within an XCD, tiles issue heavy-first.
// ---------------------------------------------------------------------------
__global__ __launch_bounds__(256, 3) void flash_attn(
    const __bf16* __restrict__ Qb, const __bf16* __restrict__ Kb,
    const __bf16* __restrict__ VTb, const int* __restrict__ amask,
    __bf16* __restrict__ Yb) {
  const int bid = blockIdx.x;
  const int xcd = bid & 7, j = bid >> 3;
  const int bh = xcd * 6 + (j >> 4);     // 6 (b,h) pairs per XCD
  const int T = 15 - (j & 15);           // heavy tiles first
  const int b = bh / Hh, h = bh - b * Hh;
  const int tid = threadIdx.x, w = tid >> 6, lane = tid & 63;
  const int hl = lane >> 5, l31 = lane & 31;
  const __bf16* Qp = Qb + (size_t)bh * Ss * Dd;
  const __bf16* Kp = Kb + (size_t)bh * Ss * Dd;
  const __bf16* Vp = VTb + (size_t)bh * Dd * Ss;

  __shared__ __align__(16) __bf16 KtP[64][72];  // permuted [key][d-slot]
  __shared__ __align__(16) __bf16 VtP[64][72];  // permuted [d][key-slot]

  const int qb = T * 128 + w * 32;  // wave's 32-query strip
  const int qg = qb + l31;          // this lane's query

  // Q as B-operand fragments, one per d-window (Q already has 1/8 folded in)
  bf16x8 qf[4];
#pragma unroll
  for (int wd = 0; wd < 4; ++wd) {
    bf16x4 a0 = *(const bf16x4*)&Qp[(size_t)qg * Dd + wd * 16 + hl * 4];
    bf16x4 a1 = *(const bf16x4*)&Qp[(size_t)qg * Dd + wd * 16 + 8 + hl * 4];
    qf[wd] = bf16x8{a0[0], a0[1], a0[2], a0[3], a1[0], a1[1], a1[2], a1[3]};
  }

  f32x16 yacc[2] = {};          // Y^T[d = 32dt + (reg&3)+8(reg>>2)+4hl][q=l31]
  float m_i = -1e4f, l_i = 0.f;

  const int nkt = 2 * T + 2;
  for (int kt = 0; kt < nkt; ++kt) {
    const int k0 = kt * 64;
    __syncthreads();
    // stage K and V^T tiles into permuted LDS (4 chunks per thread)
#pragma unroll
    for (int i = 0; i < 2; ++i) {
      const int c = i * 256 + tid;
      const int row = c >> 3, cc = c & 7;      // row: key for K, d for V
      const int wd = cc >> 1, u = cc & 1;
      bf16x8 kv = *(const bf16x8*)&Kp[(size_t)(k0 + row) * Dd + cc * 8];
      *(bf16x4*)&KtP[row][wd * 16 + u * 4] = bf16x4{kv[0], kv[1], kv[2], kv[3]};
      *(bf16x4*)&KtP[row][wd * 16 + 8 + u * 4] =
          bf16x4{kv[4], kv[5], kv[6], kv[7]};
      bf16x8 vv = *(const bf16x8*)&Vp[(size_t)row * Ss + k0 + cc * 8];
      *(bf16x4*)&VtP[row][wd * 16 + u * 4] = bf16x4{vv[0], vv[1], vv[2], vv[3]};
      *(bf16x4*)&VtP[row][wd * 16 + 8 + u * 4] =
          bf16x4{vv[4], vv[5], vv[6], vv[7]};
    }
    const uint64_t mball = __ballot(amask[b * Ss + k0 + lane] != 0);
    __syncthreads();

    if (k0 > qb + 31) continue;  // wave fully above diagonal; barriers stay
                                 // aligned (no barrier below in this loop)

    // S^T = K @ Q^T over two 32-key groups, 4 d-windows each
    f32x16 sg[2];
#pragma unroll
    for (int g = 0; g < 2; ++g) {
      f32x16 acc = {};
#pragma unroll
      for (int wd = 0; wd < 4; ++wd) {
        const bf16x8 kf =
            *(const bf16x8*)&KtP[g * 32 + l31][wd * 16 + hl * 8];
        acc = MFMA32(kf, qf[wd], acc);
      }
      sg[g] = acc;
    }

    // causal mask: only this wave's single partial-diagonal iteration
    if (k0 + 63 > qb) {
#pragma unroll
      for (int g = 0; g < 2; ++g)
#pragma unroll
        for (int r = 0; r < 16; ++r) {
          const int key = k0 + g * 32 + (r & 3) + 8 * (r >> 2) + 4 * hl;
          sg[g][r] = (key <= qg) ? sg[g][r] : -30000.f;
        }
    }
    // attention mask: wave-uniform skip when tile fully valid (common case)
    if (mball != ~0ull) {
#pragma unroll
      for (int g = 0; g < 2; ++g)
#pragma unroll
        for (int r = 0; r < 16; ++r) {
          const int kr = g * 32 + (r & 3) + 8 * (r >> 2) + 4 * hl;
          sg[g][r] = ((mball >> kr) & 1) ? sg[g][r] : -30000.f;
        }
    }

    // online softmax; row = lane's q, split across lane halves -> 1 shuffle
    float mx = sg[0][0];
#pragma unroll
    for (int r = 1; r < 16; ++r) mx = fmaxf(mx, sg[0][r]);
#pragma unroll
    for (int r = 0; r < 16; ++r) mx = fmaxf(mx, sg[1][r]);
    mx = fmaxf(mx, __shfl_xor(mx, 32));
    const float mnew = fmaxf(m_i, mx);
    const float alpha = __expf(m_i - mnew);
    float rs = 0.f;
#pragma unroll
    for (int g = 0; g < 2; ++g)
#pragma unroll
      for (int r = 0; r < 16; ++r) {
        const float e = __expf(sg[g][r] - mnew);
        sg[g][r] = e;
        rs += e;
      }
    rs += __shfl_xor(rs, 32);
    l_i = l_i * alpha + rs;
    m_i = mnew;
#pragma unroll
    for (int dt = 0; dt < 2; ++dt)
#pragma unroll
      for (int r = 0; r < 16; ++r) yacc[dt][r] *= alpha;

    // P^T B-fragments: contiguous C-register groups (shared permutation)
    bf16x8 pf[4];
#pragma unroll
    for (int W = 0; W < 4; ++W) {
      bf16x8 f;
#pragma unroll
      for (int jj = 0; jj < 8; ++jj)
        f[jj] = (__bf16)sg[W >> 1][8 * (W & 1) + jj];
      pf[W] = f;
    }

    // Y^T += V^T @ P^T
#pragma unroll
    for (int dt = 0; dt < 2; ++dt)
#pragma unroll
      for (int W = 0; W < 4; ++W) {
        const bf16x8 vf =
            *(const bf16x8*)&VtP[dt * 32 + l31][W * 16 + hl * 8];
        yacc[dt] = MFMA32(vf, pf[W], yacc[dt]);
      }
  }

  // normalize; write Y [B,S,E] bf16 (8 packed 8B stores per lane)
  const float inv = 1.f / l_i;
  __bf16* yrow = Yb + (size_t)(b * Ss + qg) * Ee + h * Dd;
#pragma unroll
  for (int dt = 0; dt < 2; ++dt)
#pragma unroll
    for (int s = 0; s < 4; ++s) {
      bf16x4 o;
#pragma unroll
      for (int r = 0; r < 4; ++r) o[r] = (__bf16)(yacc[dt][s * 4 + r] * inv);
      *(bf16x4*)&yrow[dt * 32 + s * 8 + hl * 4] = o;
    }
}

// ---------------------------------------------------------------------------
// launch
// ---------------------------------------------------------------------------
extern "C" void kernel_launch(void* const* d_in, const int* in_sizes, int n_in,
                              void* d_out, int out_size, void* d_ws,
                              size_t ws_size, hipStream_t stream) {
  const float* x      = (const float*)d_in[0];
  const float* W_attn = (const float*)d_in[1];
  const float* b_attn = (const float*)d_in[2];
  const float* W_proj = (const float*)d_in[3];
  const float* b_proj = (const float*)d_in[4];
  const int* att_mask = (const int*)d_in[5];
  float* out = (float*)d_out;

  char* ws = (char*)d_ws;
  __bf16* xb  = (__bf16*)(ws);              // 12,582,912  x as bf16 / later Y
  __bf16* Wat = (__bf16*)(ws + 12582912);   //  3,538,944  W_attn^T bf16
  __bf16* Wpt = (__bf16*)(ws + 16121856);   //  1,179,648  W_proj^T bf16
  __bf16* Qb  = (__bf16*)(ws + 17301504);   // 12,582,912  Q [B,H,S,D] (x 1/8)
  __bf16* Kb  = (__bf16*)(ws + 29884416);   // 12,582,912  K [B,H,S,D]
  __bf16* VTb = (__bf16*)(ws + 42467328);   // 12,582,912  V^T [B,H,D,S]
  __bf16* Yb  = xb;

  cast_f32_bf16<<<6144, 256, 0, stream>>>(x, xb, Bb * Ss * Ee);
  transpose_cast<<<dim3(36, 12), 256, 0, stream>>>(W_attn, Wat, Ee, 3 * Ee);
  transpose_cast<<<dim3(12, 12), 256, 0, stream>>>(W_proj, Wpt, Ee, Ee);

  gemm_bt<0><<<dim3(18, 64), 256, 0, stream>>>(xb, Wat, b_attn, Qb, Kb, VTb,
                                               nullptr, Ee, 3 * Ee);
  flash_attn<<<768, 256, 0, stream>>>(Qb, Kb, VTb, att_mask, Yb);
  gemm_bt<1><<<dim3(6, 64), 256, 0, stream>>>(Yb, Wpt, b_proj, nullptr,
                                              nullptr, nullptr, out, Ee, Ee);
}

// Round 4
// 231.545 us; speedup vs baseline: 1.7332x; 1.0272x over previous
//
#include <hip/hip_runtime.h>
#include <cstdint>

// ---------------------------------------------------------------------------
// Causal self-attention block: qkv GEMM -> flash attention (32x32 MFMA,
// async 3-buffer staging) -> proj GEMM. bf16 MFMA, fp32 accumulate.
// B=4 S=2048 E=768 H=12 D=64.
// ---------------------------------------------------------------------------

typedef __bf16 bf16x8 __attribute__((ext_vector_type(8)));
typedef __bf16 bf16x4 __attribute__((ext_vector_type(4)));
typedef float  f32x4  __attribute__((ext_vector_type(4)));
typedef float  f32x16 __attribute__((ext_vector_type(16)));

#define MFMA16(a, b, c) __builtin_amdgcn_mfma_f32_16x16x32_bf16(a, b, c, 0, 0, 0)
#define MFMA32(a, b, c) __builtin_amdgcn_mfma_f32_32x32x16_bf16(a, b, c, 0, 0, 0)

static constexpr int Bb = 4, Ss = 2048, Ee = 768, Hh = 12, Dd = 64;
// softmax scale 1/8 folded with log2(e) so we can use raw v_exp_f32 (2^x)
#define QSCALE 0.18033688011112042f

__device__ __forceinline__ void gl2lds16(const void* g, void* l) {
  __builtin_amdgcn_global_load_lds(
      (const __attribute__((address_space(1))) void*)g,
      (__attribute__((address_space(3))) void*)l, 16, 0, 0);
}

__device__ __forceinline__ float fexp2(float x) {
#if __has_builtin(__builtin_amdgcn_exp2f)
  return __builtin_amdgcn_exp2f(x);
#else
  return exp2f(x);
#endif
}

// swap bits 2<->3: the shared MFMA k-slot permutation baked into Q/K/V layouts
__device__ __forceinline__ int swap23(int x) {
  return (x & ~12) | ((x & 4) << 1) | ((x & 8) >> 1);
}

// ---------------------------------------------------------------------------
// prep kernels
// ---------------------------------------------------------------------------
__global__ void cast_f32_bf16(const float* __restrict__ x,
                              __bf16* __restrict__ y, int n) {
  int i = (blockIdx.x * blockDim.x + threadIdx.x) * 4;
  if (i < n) {
    float4 v = *(const float4*)(x + i);
    bf16x4 o = {(__bf16)v.x, (__bf16)v.y, (__bf16)v.z, (__bf16)v.w};
    *(bf16x4*)(y + i) = o;
  }
}

__global__ void transpose_cast(const float* __restrict__ W,
                               __bf16* __restrict__ Wt, int K, int N) {
  __shared__ float t[64][65];
  const int k0 = blockIdx.y * 64, n0 = blockIdx.x * 64;
#pragma unroll
  for (int i = 0; i < 16; ++i) {
    int lin = i * 256 + threadIdx.x;
    int r = lin >> 6, c = lin & 63;
    t[r][c] = W[(size_t)(k0 + r) * N + n0 + c];
  }
  __syncthreads();
#pragma unroll
  for (int i = 0; i < 16; ++i) {
    int lin = i * 256 + threadIdx.x;
    int r = lin >> 6, c = lin & 63;
    Wt[(size_t)(n0 + r) * K + k0 + c] = (__bf16)t[c][r];
  }
}

// ---------------------------------------------------------------------------
// m97-style GEMM: C[M,N] = A[M,K] @ Bt[N,K]^T, 128x128 tile, BK=32.
// MODE 0: qkv epilogue -- bias; Q scaled by log2(e)/8; Q/K d-index and V^T
//         s-index permuted via swap23 (flash fragment layout).
// MODE 1: proj epilogue (bias, fp32 out)
// ---------------------------------------------------------------------------
template <int MODE>
__global__ __launch_bounds__(256) void gemm_bt(
    const __bf16* __restrict__ A, const __bf16* __restrict__ Bt,
    const float* __restrict__ bias, __bf16* __restrict__ Qb,
    __bf16* __restrict__ Kb, __bf16* __restrict__ VTb,
    float* __restrict__ out, int K, int N) {
  __shared__ __align__(16) __bf16 As[128 * 32];
  __shared__ __align__(16) __bf16 Bs[128 * 32];
  const int tid = threadIdx.x;
  const int wave = tid >> 6, lane = tid & 63;
  const int quad = lane >> 4, c16 = lane & 15;
  const int m0 = blockIdx.y * 128, n0 = blockIdx.x * 128;
  const int wm = (wave >> 1) * 64, wn = (wave & 1) * 64;

  f32x4 acc[4][4] = {};

  for (int k0 = 0; k0 < K; k0 += 32) {
    __syncthreads();
#pragma unroll
    for (int i = 0; i < 2; ++i) {
      const int cb = (i * 4 + wave) * 64;
      const int c = cb + lane;
      const int row = c >> 2, kk = (c & 3) * 8;
      gl2lds16(&A[(size_t)(m0 + row) * K + k0 + kk], &As[cb * 8]);
      gl2lds16(&Bt[(size_t)(n0 + row) * K + k0 + kk], &Bs[cb * 8]);
    }
    __syncthreads();
    bf16x8 af[4], bf[4];
#pragma unroll
    for (int mi = 0; mi < 4; ++mi)
      af[mi] = *(const bf16x8*)&As[(wm + mi * 16 + c16) * 32 + quad * 8];
#pragma unroll
    for (int ni = 0; ni < 4; ++ni)
      bf[ni] = *(const bf16x8*)&Bs[(wn + ni * 16 + c16) * 32 + quad * 8];
#pragma unroll
    for (int mi = 0; mi < 4; ++mi)
#pragma unroll
      for (int ni = 0; ni < 4; ++ni)
        acc[mi][ni] = MFMA16(af[mi], bf[ni], acc[mi][ni]);
  }

#pragma unroll
  for (int mi = 0; mi < 4; ++mi) {
#pragma unroll
    for (int ni = 0; ni < 4; ++ni) {
      const int gcol = n0 + wn + ni * 16 + c16;
      const float bv = bias[gcol];
      const int growb = m0 + wm + mi * 16 + quad * 4;
      if (MODE == 0) {
        const int which = gcol / Ee;
        const int e = gcol - which * Ee;
        const int hh = e >> 6, dd = e & 63;
        const int bb = growb >> 11, ss = growb & 2047;
        const size_t bh = (size_t)(bb * Hh + hh);
        if (which == 2) {  // V^T with permuted s: 4 consecutive ss stay packed
          const int ssp = swap23(ss);
          bf16x4 o;
#pragma unroll
          for (int r = 0; r < 4; ++r) o[r] = (__bf16)(acc[mi][ni][r] + bv);
          *(bf16x4*)&VTb[(bh * Dd + dd) * Ss + ssp] = o;
        } else if (which == 0) {  // Q: permuted d, prescaled
          const int ddp = swap23(dd);
#pragma unroll
          for (int r = 0; r < 4; ++r)
            Qb[(bh * Ss + ss + r) * Dd + ddp] =
                (__bf16)((acc[mi][ni][r] + bv) * QSCALE);
        } else {  // K: permuted d
          const int ddp = swap23(dd);
#pragma unroll
          for (int r = 0; r < 4; ++r)
            Kb[(bh * Ss + ss + r) * Dd + ddp] = (__bf16)(acc[mi][ni][r] + bv);
        }
      } else {
#pragma unroll
        for (int r = 0; r < 4; ++r)
          out[(size_t)(growb + r) * N + gcol] = acc[mi][ni][r] + bv;
      }
    }
  }
}

// ---------------------------------------------------------------------------
// flash attention v4: 32x32x16 MFMA; block = 4 waves with balanced strips
// {b, 31-b, 32+b, 63-b} (32 queries each) so every block has equal work.
// Async 3-buffer K/V staging via global_load_lds with XOR-(row&7) 16B-chunk
// swizzle (conflict-free b128 frag reads, no padding). One raw s_barrier +
// partial vmcnt wait per iteration -- prefetch issued a full iter ahead.
// Q/K/V global layouts carry the swap23 k-slot permutation (from gemm1).
// ---------------------------------------------------------------------------
__global__ __launch_bounds__(256, 3) void flash_attn(
    const __bf16* __restrict__ Qb, const __bf16* __restrict__ Kb,
    const __bf16* __restrict__ VTb, const int* __restrict__ amask,
    __bf16* __restrict__ Yb) {
  const int bid = blockIdx.x;
  const int xcd = bid & 7, j = bid >> 3;
  const int bh = xcd * 6 + (j >> 4);  // 6 (b,h) per XCD for L2 locality
  const int bidx = j & 15;
  const int b = bh / Hh, h = bh - b * Hh;
  const int tid = threadIdx.x, w = tid >> 6, lane = tid & 63;
  const int hl = lane >> 5, l31 = lane & 31;
  const int r7 = l31 & 7;

  // balanced strip assignment: w=0:b, w=1:31-b, w=2:32+b, w=3:63-b
  const int s = ((w & 2) << 4) + ((w & 1) ? 31 - bidx : bidx);
  const int qs = s * 32;
  const int qg = qs + l31;     // this lane's query
  const int ktmax = s >> 1;    // last key-tile this wave participates in
  const int nkt = ((63 - bidx) >> 1) + 1;  // block-uniform iteration count

  const __bf16* Qp = Qb + (size_t)bh * Ss * Dd;
  const __bf16* Kp = Kb + (size_t)bh * Ss * Dd;
  const __bf16* Vp = VTb + (size_t)bh * Dd * Ss;

  __shared__ __align__(16) __bf16 Ksh[3 * 64 * 64];  // 3 x 8KB
  __shared__ __align__(16) __bf16 Vsh[3 * 64 * 64];  // 3 x 8KB
  __shared__ uint64_t ballots[32];

  // Q fragments: contiguous b128 thanks to permuted global layout
  bf16x8 qf[4];
#pragma unroll
  for (int wd = 0; wd < 4; ++wd)
    qf[wd] = *(const bf16x8*)&Qp[(size_t)qg * Dd + wd * 16 + hl * 8];

  // precompute attention-mask ballots for all 32 key-tiles (8 per wave)
#pragma unroll
  for (int i = 0; i < 8; ++i) {
    const int t = w * 8 + i;
    const uint64_t ball = __ballot(amask[b * Ss + t * 64 + lane] != 0);
    if (lane == 0) ballots[t] = ball;
  }
  asm volatile("s_waitcnt lgkmcnt(0)" ::: "memory");  // publish ballots

  // async stage of tile kt into buffer buf (4 gl2lds16 per thread)
  auto stage = [&](int kt, int buf) {
    __bf16* kb = &Ksh[buf * 4096];
    __bf16* vb = &Vsh[buf * 4096];
    const char* ksrc = (const char*)(Kp + (size_t)kt * 64 * Dd);
    const char* vsrc = (const char*)Vp + (size_t)kt * 128;
#pragma unroll
    for (int i = 0; i < 2; ++i) {
      const int cb = i * 256 + w * 64;        // wave-uniform chunk base
      const int p = cb + lane;                // this lane's chunk 0..511
      const int row = p >> 3;
      const int cc = (p & 7) ^ (row & 7);     // XOR swizzle
      gl2lds16(ksrc + (size_t)row * 128 + cc * 16, &kb[cb * 8]);
      gl2lds16(vsrc + (size_t)row * 4096 + cc * 16, &vb[cb * 8]);
    }
  };

  stage(0, 0);
  if (nkt > 1) stage(1, 1);

  f32x16 yacc[2] = {};  // Y^T[d = 32dt + (r&3)+8(r>>2)+4hl][q = l31]
  float m_i = -30000.f, l_i = 0.f;

  for (int kt = 0; kt < nkt; ++kt) {
    // wait for tile kt's staging (keep kt+1's 4 loads in flight), then
    // barrier: publishes buf[kt] and proves everyone left buf[(kt+2)%3]
    if (kt + 1 < nkt)
      asm volatile("s_waitcnt vmcnt(4)\n\ts_barrier" ::: "memory");
    else
      asm volatile("s_waitcnt vmcnt(0)\n\ts_barrier" ::: "memory");
    if (kt + 2 < nkt) stage(kt + 2, (kt + 2) % 3);

    if (kt > ktmax) continue;  // wave above diagonal: staging-only helper
    const int k0 = kt * 64;
    const __bf16* kb = &Ksh[(kt % 3) * 4096];
    const __bf16* vb = &Vsh[(kt % 3) * 4096];

    // S^T = K @ Q^T over two 32-key groups (C rows = keys, cols = queries)
    f32x16 sg[2];
#pragma unroll
    for (int g = 0; g < 2; ++g) {
      f32x16 acc = {};
#pragma unroll
      for (int wd = 0; wd < 4; ++wd) {
        const bf16x8 kf = *(const bf16x8*)&kb[(g * 32 + l31) * 64 +
                                             (((2 * wd + hl) ^ r7) * 8)];
        acc = MFMA32(kf, qf[wd], acc);
      }
      sg[g] = acc;
    }

    // causal mask: only tiles overlapping this wave's diagonal
    if (k0 + 63 > qs) {
#pragma unroll
      for (int g = 0; g < 2; ++g)
#pragma unroll
        for (int r = 0; r < 16; ++r) {
          const int key = k0 + g * 32 + (r & 3) + 8 * (r >> 2) + 4 * hl;
          sg[g][r] = (key <= qg) ? sg[g][r] : -30000.f;
        }
    }
    // attention mask: wave-uniform skip when tile fully valid
    const uint64_t mball = ballots[kt];
    if (mball != ~0ull) {
#pragma unroll
      for (int g = 0; g < 2; ++g)
#pragma unroll
        for (int r = 0; r < 16; ++r) {
          const int kr = g * 32 + (r & 3) + 8 * (r >> 2) + 4 * hl;
          sg[g][r] = ((mball >> kr) & 1) ? sg[g][r] : -30000.f;
        }
    }

    // online softmax in log2 domain; row = lane's q; 1 cross-half shuffle
    float mx = sg[0][0];
#pragma unroll
    for (int r = 1; r < 16; ++r) mx = fmaxf(mx, sg[0][r]);
#pragma unroll
    for (int r = 0; r < 16; ++r) mx = fmaxf(mx, sg[1][r]);
    mx = fmaxf(mx, __shfl_xor(mx, 32));
    const float mnew = fmaxf(m_i, mx);
    const float alpha = fexp2(m_i - mnew);
    float rs = 0.f;
#pragma unroll
    for (int g = 0; g < 2; ++g)
#pragma unroll
      for (int r = 0; r < 16; ++r) {
        const float e = fexp2(sg[g][r] - mnew);
        sg[g][r] = e;
        rs += e;
      }
    rs += __shfl_xor(rs, 32);
    l_i = l_i * alpha + rs;
    m_i = mnew;
#pragma unroll
    for (int dt = 0; dt < 2; ++dt)
#pragma unroll
      for (int r = 0; r < 16; ++r) yacc[dt][r] *= alpha;

    // P^T B-fragments = S^T C-register groups (shared k-slot permutation)
    bf16x8 pf[4];
#pragma unroll
    for (int W = 0; W < 4; ++W) {
      bf16x8 f;
#pragma unroll
      for (int jj = 0; jj < 8; ++jj)
        f[jj] = (__bf16)sg[W >> 1][8 * (W & 1) + jj];
      pf[W] = f;
    }

    // Y^T += V^T @ P^T
#pragma unroll
    for (int dt = 0; dt < 2; ++dt)
#pragma unroll
      for (int W = 0; W < 4; ++W) {
        const bf16x8 vf = *(const bf16x8*)&vb[(dt * 32 + l31) * 64 +
                                             (((2 * W + hl) ^ r7) * 8)];
        yacc[dt] = MFMA32(vf, pf[W], yacc[dt]);
      }
  }

  // normalize; write Y [B,S,E] bf16 (unpermuted -- feeds gemm2)
  const float inv = 1.f / l_i;
  __bf16* yrow = Yb + (size_t)(b * Ss + qg) * Ee + h * Dd;
#pragma unroll
  for (int dt = 0; dt < 2; ++dt)
#pragma unroll
    for (int sreg = 0; sreg < 4; ++sreg) {
      bf16x4 o;
#pragma unroll
      for (int r = 0; r < 4; ++r)
        o[r] = (__bf16)(yacc[dt][sreg * 4 + r] * inv);
      *(bf16x4*)&yrow[dt * 32 + sreg * 8 + hl * 4] = o;
    }
}

// ---------------------------------------------------------------------------
// launch
// ---------------------------------------------------------------------------
extern "C" void kernel_launch(void* const* d_in, const int* in_sizes, int n_in,
                              void* d_out, int out_size, void* d_ws,
                              size_t ws_size, hipStream_t stream) {
  const float* x      = (const float*)d_in[0];
  const float* W_attn = (const float*)d_in[1];
  const float* b_attn = (const float*)d_in[2];
  const float* W_proj = (const float*)d_in[3];
  const float* b_proj = (const float*)d_in[4];
  const int* att_mask = (const int*)d_in[5];
  float* out = (float*)d_out;

  char* ws = (char*)d_ws;
  __bf16* xb  = (__bf16*)(ws);              // 12,582,912  x as bf16 / later Y
  __bf16* Wat = (__bf16*)(ws + 12582912);   //  3,538,944  W_attn^T bf16
  __bf16* Wpt = (__bf16*)(ws + 16121856);   //  1,179,648  W_proj^T bf16
  __bf16* Qb  = (__bf16*)(ws + 17301504);   // Q [B,H,S,D] perm, x log2e/8
  __bf16* Kb  = (__bf16*)(ws + 29884416);   // K [B,H,S,D] perm
  __bf16* VTb = (__bf16*)(ws + 42467328);   // V^T [B,H,D,S] perm
  __bf16* Yb  = xb;

  cast_f32_bf16<<<6144, 256, 0, stream>>>(x, xb, Bb * Ss * Ee);
  transpose_cast<<<dim3(36, 12), 256, 0, stream>>>(W_attn, Wat, Ee, 3 * Ee);
  transpose_cast<<<dim3(12, 12), 256, 0, stream>>>(W_proj, Wpt, Ee, Ee);

  gemm_bt<0><<<dim3(18, 64), 256, 0, stream>>>(xb, Wat, b_attn, Qb, Kb, VTb,
                                               nullptr, Ee, 3 * Ee);
  flash_attn<<<768, 256, 0, stream>>>(Qb, Kb, VTb, att_mask, Yb);
  gemm_bt<1><<<dim3(6, 64), 256, 0, stream>>>(Yb, Wpt, b_proj, nullptr,
                                              nullptr, nullptr, out, Ee, Ee);
}